// Round 7
// baseline (3026.312 us; speedup 1.0000x reference)
//
#include <hip/hip_runtime.h>

#define NA 10000
#define NE 320000

typedef short short8 __attribute__((ext_vector_type(8)));
typedef unsigned short us4 __attribute__((ext_vector_type(4)));
typedef float f32x4 __attribute__((ext_vector_type(4)));

__device__ __forceinline__ float silu_f(float v) { return v / (1.0f + __expf(-v)); }

__device__ __forceinline__ void split_bf16(float x, unsigned short& h, unsigned short& l)
{
    unsigned int u = __float_as_uint(x);
    h = (unsigned short)(u >> 16);
    float hf = __uint_as_float((unsigned int)h << 16);
    unsigned int ul = __float_as_uint(x - hf) + 0x8000u;
    l = (unsigned short)(ul >> 16);
}

// ---------------- init ----------------------------------------------------------
__global__ __launch_bounds__(256) void k_init(
    const int* __restrict__ Z, const int* __restrict__ idx_m,
    const float* __restrict__ emb, const float* __restrict__ e_field,
    float* __restrict__ q, float* __restrict__ mu,
    float* __restrict__ Eat, int* __restrict__ counts, int* __restrict__ cursor)
{
    int gid = blockIdx.x * 256 + threadIdx.x;
    if (gid < NA * 384) mu[gid] = 0.0f;
    if (gid < NA * 128) {
        int i = gid >> 7, f = gid & 127;
        q[gid] = emb[Z[i] * 128 + f];
    }
    if (gid < NA * 3) {
        int i = gid / 3, d = gid - i * 3;
        Eat[gid] = e_field[idx_m[i] * 3 + d];
    }
    if (gid < NA) { counts[gid] = 0; cursor[gid] = 0; }
}

// ---------------- histogram idx_i -----------------------------------------------
__global__ __launch_bounds__(256) void k_count(
    const int* __restrict__ idx_i, int* __restrict__ counts)
{
    int e = blockIdx.x * 256 + threadIdx.x;
    if (e < NE) atomicAdd(&counts[idx_i[e]], 1);
}

// ---------------- exclusive scan -------------------------------------------------
__global__ __launch_bounds__(256) void k_scan(const int* __restrict__ counts,
                                              int* __restrict__ rowptr)
{
    __shared__ int part[256];
    int tid = threadIdx.x;
    const int CH = (NA + 255) / 256;
    int base = tid * CH;
    int s = 0;
    for (int i2 = 0; i2 < CH; i2++) {
        int idx = base + i2;
        if (idx < NA) s += counts[idx];
    }
    part[tid] = s;
    __syncthreads();
    for (int ofs = 1; ofs < 256; ofs <<= 1) {
        int v = part[tid];
        int add = (tid >= ofs) ? part[tid - ofs] : 0;
        __syncthreads();
        part[tid] = v + add;
        __syncthreads();
    }
    int run = (tid > 0) ? part[tid - 1] : 0;
    for (int i2 = 0; i2 < CH; i2++) {
        int idx = base + i2;
        if (idx < NA) { rowptr[idx] = run; run += counts[idx]; }
        else if (idx == NA) rowptr[NA] = run;
    }
}

// ---------------- geometry + scatter into CSR order -----------------------------
__global__ __launch_bounds__(256) void k_geom_scatter(
    const float* __restrict__ r_ij, const int* __restrict__ idx_i,
    const int* __restrict__ idx_j, const int* __restrict__ rowptr,
    int* __restrict__ cursor, float* __restrict__ phi_s,
    float4* __restrict__ df_s, int* __restrict__ j_s)
{
    int e = blockIdx.x * 256 + threadIdx.x;
    if (e >= NE) return;
    float x = r_ij[e*3+0], y = r_ij[e*3+1], z = r_ij[e*3+2];
    float d = sqrtf(x*x + y*y + z*z);
    float inv = 1.0f / d;
    float fc = (d < 5.0f) ? 0.5f * (__cosf(d * 0.628318530717958648f) + 1.0f) : 0.0f;
    int i = idx_i[e];
    int pos = rowptr[i] + atomicAdd(&cursor[i], 1);
    float4 dv; dv.x = x*inv; dv.y = y*inv; dv.z = z*inv; dv.w = fc;
    df_s[pos] = dv;
    j_s[pos] = idx_j[e];
    const float invw = 19.0f / 5.0f;
    float ph[20];
    #pragma unroll
    for (int k = 0; k < 20; k++) {
        float off = (5.0f / 19.0f) * (float)k;
        float u = (d - off) * invw;
        ph[k] = __expf(-0.5f * u * u) * fc;
    }
    #pragma unroll
    for (int c = 0; c < 5; c++) {
        float4 pv; pv.x = ph[c*4]; pv.y = ph[c*4+1]; pv.z = ph[c*4+2]; pv.w = ph[c*4+3];
        *(float4*)(phi_s + (size_t)pos*20 + c*4) = pv;
    }
}

// ---------------- weight prep: hi/lo bf16 split, MFMA-fragment-linear -----------
struct WDesc { const float* src; unsigned short* dh; unsigned short* dl; int K; int N; };
struct WPack { WDesc w[24]; };

__global__ __launch_bounds__(256) void k_wprep(WPack P)
{
    WDesc d = P.w[blockIdx.y];
    int kBlks = d.K >> 5, nStrips = d.N >> 4;
    int total = nStrips * kBlks * 64;
    int g = blockIdx.x * 256 + threadIdx.x;
    if (g >= total) return;
    int lane = g & 63, rem = g >> 6;
    int kb = rem % kBlks, sIdx = rem / kBlks;
    int m16 = lane & 15, quad = lane >> 4;
    int n = sIdx * 16 + m16;
    int kbase = kb * 32 + quad * 8;
    size_t dofs = (size_t)g * 8;
    #pragma unroll
    for (int jj = 0; jj < 8; jj++) {
        unsigned short h, l;
        split_bf16(d.src[(size_t)(kbase + jj) * d.N + n], h, l);
        d.dh[dofs + jj] = h;
        d.dl[dofs + jj] = l;
    }
}

// ---------------- MFMA GEMM (bf16 split-3), 64x64 tile --------------------------
template<int ACT>
__global__ __launch_bounds__(256) void k_gmm2(
    const float* __restrict__ A,
    const unsigned short* __restrict__ Bh, const unsigned short* __restrict__ Bl,
    const float* __restrict__ bias, float* __restrict__ C,
    int M, int K, int N)
{
    __shared__ unsigned short Ahs[64 * 40];
    __shared__ unsigned short Als[64 * 40];
    int tid = threadIdx.x, lane = tid & 63, wv = tid >> 6;
    int i0 = blockIdx.x * 64, n0 = blockIdx.y * 64;
    int m16 = lane & 15, quad = lane >> 4;
    int kBlks = K >> 5;
    int sIdx = blockIdx.y * 4 + wv;

    f32x4 acc[4];
    #pragma unroll
    for (int a = 0; a < 4; a++) acc[a] = 0.0f;

    for (int kb = 0; kb < kBlks; kb++) {
        int k0 = kb << 5;
        __syncthreads();
        #pragma unroll
        for (int s = 0; s < 2; s++) {
            int idx = s * 256 + tid;
            int r = idx >> 3, c4 = (idx & 7) << 2;
            float4 v = {0.f, 0.f, 0.f, 0.f};
            if (i0 + r < M) v = *(const float4*)(A + (size_t)(i0 + r) * K + k0 + c4);
            unsigned short h0,l0,h1,l1,h2,l2,h3,l3;
            split_bf16(v.x, h0, l0); split_bf16(v.y, h1, l1);
            split_bf16(v.z, h2, l2); split_bf16(v.w, h3, l3);
            us4 hv = {h0, h1, h2, h3}, lv = {l0, l1, l2, l3};
            *(us4*)(Ahs + r * 40 + c4) = hv;
            *(us4*)(Als + r * 40 + c4) = lv;
        }
        __syncthreads();
        size_t bofs = (((size_t)sIdx * kBlks + kb) * 64 + lane) * 8;
        short8 bh = *(const short8*)(Bh + bofs);
        short8 bl = *(const short8*)(Bl + bofs);
        #pragma unroll
        for (int tm = 0; tm < 4; tm++) {
            short8 ah = *(const short8*)(Ahs + (tm * 16 + m16) * 40 + quad * 8);
            short8 al = *(const short8*)(Als + (tm * 16 + m16) * 40 + quad * 8);
            acc[tm] = __builtin_amdgcn_mfma_f32_16x16x32_bf16(ah, bh, acc[tm], 0, 0, 0);
            acc[tm] = __builtin_amdgcn_mfma_f32_16x16x32_bf16(ah, bl, acc[tm], 0, 0, 0);
            acc[tm] = __builtin_amdgcn_mfma_f32_16x16x32_bf16(al, bh, acc[tm], 0, 0, 0);
        }
    }
    int col = n0 + wv * 16 + m16;
    float bv = bias ? bias[col] : 0.0f;
    #pragma unroll
    for (int tm = 0; tm < 4; tm++) {
        #pragma unroll
        for (int r = 0; r < 4; r++) {
            int row = i0 + tm * 16 + quad * 4 + r;
            if (row < M) {
                float v = acc[tm][r] + bv;
                if (ACT) v = silu_f(v);
                C[(size_t)row * N + col] = v;
            }
        }
    }
}

// ---------------- fused MLP with prologue/epilogue variants ----------------------
// PRO: 0 = A is [M,K1] dense; 1 = ctx mode (K1=256): cols 0..127 from q (stride
//      128), cols 128..255 = ||mu_V|| computed from mumix on the fly.
// EPI: 0 = write C = h2 + b2
//      1 = field: a_s = h2+b2 consumed in-place -> mu += a_s*E - (a_v.E)a_v
//      2 = mixupd: y staged in LDS; q += yq + yqm*sdot; mu += ym*mu_W;
//          if last, also write packed out [N,4,128].
template<int K1, int N2, int PRO, int EPI>
__global__ __launch_bounds__(256, 2) void k_mlp(
    const float* __restrict__ A, const float* __restrict__ mumix,
    const unsigned short* __restrict__ B1h, const unsigned short* __restrict__ B1l,
    const float* __restrict__ b1,
    const unsigned short* __restrict__ B2h, const unsigned short* __restrict__ B2l,
    const float* __restrict__ b2,
    float* __restrict__ C,
    const float* __restrict__ av, const float* __restrict__ Eat,
    float* __restrict__ qRW, float* __restrict__ muRW,
    float* __restrict__ outPk, int last, int M)
{
    const int KB1 = K1 / 32;
    const int S2  = N2 / 64;
    __shared__ unsigned short A1h[32 * 40];
    __shared__ unsigned short A1l[32 * 40];
    __shared__ unsigned short Hh[32 * 136];
    __shared__ unsigned short Hl[32 * 136];
    __shared__ float Ys[EPI == 2 ? 32 * 384 : 1];

    int tid = threadIdx.x, lane = tid & 63, wv = tid >> 6;
    int i0 = blockIdx.x * 32;
    int m16 = lane & 15, quad = lane >> 4;

    // ---- stage 1: h = silu(A@W1 + b1) ----
    f32x4 acc1[2][2];
    #pragma unroll
    for (int s = 0; s < 2; s++)
        #pragma unroll
        for (int tm = 0; tm < 2; tm++) acc1[s][tm] = 0.0f;

    for (int kb = 0; kb < KB1; kb++) {
        int k0 = kb << 5;
        __syncthreads();
        {
            int r = tid >> 3, c4 = (tid & 7) << 2;
            int row = i0 + r;
            float4 v = {0.f, 0.f, 0.f, 0.f};
            if (row < M) {
                if (PRO == 0) {
                    v = *(const float4*)(A + (size_t)row * K1 + k0 + c4);
                } else {
                    int g = k0 + c4;
                    if (g < 128) {
                        v = *(const float4*)(A + (size_t)row * 128 + g);
                    } else {
                        int f = g - 128;
                        float4 v0 = *(const float4*)(mumix + ((size_t)row*3 + 0)*256 + f);
                        float4 v1 = *(const float4*)(mumix + ((size_t)row*3 + 1)*256 + f);
                        float4 v2 = *(const float4*)(mumix + ((size_t)row*3 + 2)*256 + f);
                        v.x = sqrtf(v0.x*v0.x + v1.x*v1.x + v2.x*v2.x + 1e-8f);
                        v.y = sqrtf(v0.y*v0.y + v1.y*v1.y + v2.y*v2.y + 1e-8f);
                        v.z = sqrtf(v0.z*v0.z + v1.z*v1.z + v2.z*v2.z + 1e-8f);
                        v.w = sqrtf(v0.w*v0.w + v1.w*v1.w + v2.w*v2.w + 1e-8f);
                    }
                }
            }
            unsigned short h0,l0,h1,l1,h2,l2,h3,l3;
            split_bf16(v.x, h0, l0); split_bf16(v.y, h1, l1);
            split_bf16(v.z, h2, l2); split_bf16(v.w, h3, l3);
            us4 hv = {h0, h1, h2, h3}, lv = {l0, l1, l2, l3};
            *(us4*)(A1h + r * 40 + c4) = hv;
            *(us4*)(A1l + r * 40 + c4) = lv;
        }
        __syncthreads();
        #pragma unroll
        for (int tm = 0; tm < 2; tm++) {
            short8 ah = *(const short8*)(A1h + (tm * 16 + m16) * 40 + quad * 8);
            short8 al = *(const short8*)(A1l + (tm * 16 + m16) * 40 + quad * 8);
            #pragma unroll
            for (int s = 0; s < 2; s++) {
                int sIdx = wv * 2 + s;
                size_t bofs = (((size_t)sIdx * KB1 + kb) * 64 + lane) * 8;
                short8 bh = *(const short8*)(B1h + bofs);
                short8 bl = *(const short8*)(B1l + bofs);
                acc1[s][tm] = __builtin_amdgcn_mfma_f32_16x16x32_bf16(ah, bh, acc1[s][tm], 0, 0, 0);
                acc1[s][tm] = __builtin_amdgcn_mfma_f32_16x16x32_bf16(ah, bl, acc1[s][tm], 0, 0, 0);
                acc1[s][tm] = __builtin_amdgcn_mfma_f32_16x16x32_bf16(al, bh, acc1[s][tm], 0, 0, 0);
            }
        }
    }
    __syncthreads();
    #pragma unroll
    for (int s = 0; s < 2; s++) {
        int col = wv * 32 + s * 16 + m16;
        float bb = b1[col];
        #pragma unroll
        for (int tm = 0; tm < 2; tm++) {
            #pragma unroll
            for (int r = 0; r < 4; r++) {
                int row = tm * 16 + quad * 4 + r;
                float v = silu_f(acc1[s][tm][r] + bb);
                unsigned short h, l;
                split_bf16(v, h, l);
                Hh[row * 136 + col] = h;
                Hl[row * 136 + col] = l;
            }
        }
    }
    __syncthreads();

    // ---- stage 2: h2 = h@W2 ----
    f32x4 acc2[S2][2];
    #pragma unroll
    for (int s = 0; s < S2; s++)
        #pragma unroll
        for (int tm = 0; tm < 2; tm++) acc2[s][tm] = 0.0f;

    #pragma unroll
    for (int kb = 0; kb < 4; kb++) {
        short8 ah[2], al[2];
        #pragma unroll
        for (int tm = 0; tm < 2; tm++) {
            ah[tm] = *(const short8*)(Hh + (tm * 16 + m16) * 136 + kb * 32 + quad * 8);
            al[tm] = *(const short8*)(Hl + (tm * 16 + m16) * 136 + kb * 32 + quad * 8);
        }
        #pragma unroll
        for (int s = 0; s < S2; s++) {
            int sIdx = wv * S2 + s;
            size_t bofs = (((size_t)sIdx * 4 + kb) * 64 + lane) * 8;
            short8 bh = *(const short8*)(B2h + bofs);
            short8 bl = *(const short8*)(B2l + bofs);
            #pragma unroll
            for (int tm = 0; tm < 2; tm++) {
                acc2[s][tm] = __builtin_amdgcn_mfma_f32_16x16x32_bf16(ah[tm], bh, acc2[s][tm], 0, 0, 0);
                acc2[s][tm] = __builtin_amdgcn_mfma_f32_16x16x32_bf16(ah[tm], bl, acc2[s][tm], 0, 0, 0);
                acc2[s][tm] = __builtin_amdgcn_mfma_f32_16x16x32_bf16(al[tm], bh, acc2[s][tm], 0, 0, 0);
            }
        }
    }

    if (EPI == 0) {
        #pragma unroll
        for (int s = 0; s < S2; s++) {
            int col = (wv * S2 + s) * 16 + m16;
            float bb = b2 ? b2[col] : 0.0f;
            #pragma unroll
            for (int tm = 0; tm < 2; tm++) {
                #pragma unroll
                for (int r = 0; r < 4; r++) {
                    int row = i0 + tm * 16 + quad * 4 + r;
                    if (row < M) C[(size_t)row * N2 + col] = acc2[s][tm][r] + bb;
                }
            }
        }
    } else if (EPI == 1) {
        // field: mu += a_s*E - (a_v.E)*a_v   (a_s = acc2+b2, consumed in-place)
        #pragma unroll
        for (int s = 0; s < S2; s++) {
            int col = (wv * S2 + s) * 16 + m16;
            float bb = b2[col];
            #pragma unroll
            for (int tm = 0; tm < 2; tm++) {
                #pragma unroll
                for (int r = 0; r < 4; r++) {
                    int row = i0 + tm * 16 + quad * 4 + r;
                    if (row < M) {
                        float as = acc2[s][tm][r] + bb;
                        float E0 = Eat[row*3+0], E1 = Eat[row*3+1], E2 = Eat[row*3+2];
                        size_t b0 = ((size_t)row*3 + 0)*128 + col;
                        size_t b1o = ((size_t)row*3 + 1)*128 + col;
                        size_t b2o = ((size_t)row*3 + 2)*128 + col;
                        float a0 = av[b0], a1 = av[b1o], a2 = av[b2o];
                        float dot = a0*E0 + a1*E1 + a2*E2;
                        muRW[b0] += as*E0 - dot*a0;
                        muRW[b1o] += as*E1 - dot*a1;
                        muRW[b2o] += as*E2 - dot*a2;
                    }
                }
            }
        }
    } else {
        // mixupd: stage y in LDS, then cross-channel update of q/mu (+ packed out)
        #pragma unroll
        for (int s = 0; s < S2; s++) {
            int col = (wv * S2 + s) * 16 + m16;
            float bb = b2[col];
            #pragma unroll
            for (int tm = 0; tm < 2; tm++) {
                #pragma unroll
                for (int r = 0; r < 4; r++) {
                    int row = tm * 16 + quad * 4 + r;
                    Ys[row * 384 + col] = acc2[s][tm][r] + bb;
                }
            }
        }
        __syncthreads();
        int f = tid & 127;
        #pragma unroll
        for (int it = 0; it < 16; it++) {
            int row = (tid >> 7) + it * 2;
            int i = i0 + row;
            if (i < M) {
                float yq  = Ys[row * 384 + f];
                float ym  = Ys[row * 384 + 128 + f];
                float yqm = Ys[row * 384 + 256 + f];
                float sdot = 0.0f;
                float W[3];
                #pragma unroll
                for (int d = 0; d < 3; d++) {
                    float Vd = mumix[((size_t)i*3 + d)*256 + f];
                    W[d]     = mumix[((size_t)i*3 + d)*256 + 128 + f];
                    sdot += Vd * W[d];
                }
                float qn = qRW[(size_t)i*128 + f] + yq + yqm * sdot;
                qRW[(size_t)i*128 + f] = qn;
                float mun[3];
                #pragma unroll
                for (int d = 0; d < 3; d++) {
                    size_t mo = ((size_t)i*3 + d)*128 + f;
                    mun[d] = muRW[mo] + ym * W[d];
                    muRW[mo] = mun[d];
                }
                if (last) {
                    outPk[(size_t)i*512 + f] = qn;
                    #pragma unroll
                    for (int d = 0; d < 3; d++)
                        outPk[(size_t)i*512 + 128 + d*128 + f] = mun[d];
                }
            }
        }
    }
}

// ---------------- edge aggregation: atom-centric, software-pipelined gathers -----
// Block = 4 waves = 2 atoms x 2 feature-halves (k_edge4 structure). The j->x/mu
// dependent-load chain is broken by prefetching next batch's j + gathers during
// the current batch's filter-dot compute.
__global__ __launch_bounds__(256, 3) void k_edge6(
    int t, const float* __restrict__ phi_s, const float4* __restrict__ df_s,
    const int* __restrict__ j_s, const int* __restrict__ rowptr,
    const float* __restrict__ x, const float* __restrict__ mu_in,
    const float* __restrict__ filt_W, const float* __restrict__ filt_b,
    float* __restrict__ q, float* __restrict__ mu_out)
{
    int lane = threadIdx.x & 63;
    int wv   = threadIdx.x >> 6;
    int ia   = blockIdx.x * 2 + (wv >> 1);
    int h    = wv & 1;
    int f    = lane + h * 64;

    float wreg[3][20];
    float b3[3];
    #pragma unroll
    for (int c = 0; c < 3; c++) {
        int col = t * 384 + (2*c + h) * 64 + lane;
        b3[c] = filt_b[col];
        #pragma unroll
        for (int k = 0; k < 20; k++)
            wreg[c][k] = filt_W[k * 1152 + col];
    }

    float accq = 0.0f, acc0 = 0.0f, acc1 = 0.0f, acc2 = 0.0f;
    int p0 = rowptr[ia], p1 = rowptr[ia + 1];
    int p = p0;

    float xv[4][3], mv[4][3];
    bool have = (p + 4 <= p1);
    if (have) {
        #pragma unroll
        for (int e = 0; e < 4; e++) {
            int j = j_s[p + e];
            size_t xb = (size_t)j * 384;
            xv[e][0] = x[xb + h*64 + lane];
            xv[e][1] = x[xb + (2+h)*64 + lane];
            xv[e][2] = x[xb + (4+h)*64 + lane];
            #pragma unroll
            for (int d = 0; d < 3; d++)
                mv[e][d] = mu_in[((size_t)j*3 + d)*128 + f];
        }
    }
    while (have) {
        int pn = p + 4;
        bool haveN = (pn + 4 <= p1);
        // current batch filter dots (streaming df/phi loads)
        float4 df[4];
        #pragma unroll
        for (int e = 0; e < 4; e++) df[e] = df_s[p + e];
        float dots[4][3];
        #pragma unroll
        for (int e = 0; e < 4; e++)
            #pragma unroll
            for (int c = 0; c < 3; c++) dots[e][c] = df[e].w * b3[c];
        #pragma unroll
        for (int kq = 0; kq < 5; kq++) {
            float4 a[4];
            #pragma unroll
            for (int e = 0; e < 4; e++)
                a[e] = *(const float4*)(phi_s + (size_t)(p + e) * 20 + kq * 4);
            #pragma unroll
            for (int e = 0; e < 4; e++) {
                #pragma unroll
                for (int c = 0; c < 3; c++) {
                    dots[e][c] = fmaf(a[e].x, wreg[c][kq*4+0], dots[e][c]);
                    dots[e][c] = fmaf(a[e].y, wreg[c][kq*4+1], dots[e][c]);
                    dots[e][c] = fmaf(a[e].z, wreg[c][kq*4+2], dots[e][c]);
                    dots[e][c] = fmaf(a[e].w, wreg[c][kq*4+3], dots[e][c]);
                }
            }
        }
        // prefetch next batch gathers (overlaps with accumulation below)
        float xn[4][3], mn[4][3];
        if (haveN) {
            #pragma unroll
            for (int e = 0; e < 4; e++) {
                int j = j_s[pn + e];
                size_t xb = (size_t)j * 384;
                xn[e][0] = x[xb + h*64 + lane];
                xn[e][1] = x[xb + (2+h)*64 + lane];
                xn[e][2] = x[xb + (4+h)*64 + lane];
                #pragma unroll
                for (int d = 0; d < 3; d++)
                    mn[e][d] = mu_in[((size_t)j*3 + d)*128 + f];
            }
        }
        // accumulate current batch
        #pragma unroll
        for (int e = 0; e < 4; e++) {
            float xxq = dots[e][0] * xv[e][0];
            float xxr = dots[e][1] * xv[e][1];
            float xxm = dots[e][2] * xv[e][2];
            accq += xxq;
            acc0 += xxr * df[e].x + xxm * mv[e][0];
            acc1 += xxr * df[e].y + xxm * mv[e][1];
            acc2 += xxr * df[e].z + xxm * mv[e][2];
        }
        #pragma unroll
        for (int e = 0; e < 4; e++) {
            #pragma unroll
            for (int c = 0; c < 3; c++) { xv[e][c] = xn[e][c]; mv[e][c] = mn[e][c]; }
        }
        p = pn;
        have = haveN;
    }
    for (; p < p1; p++) {
        int j0 = j_s[p];
        float4 d0 = df_s[p];
        float dots0[3];
        #pragma unroll
        for (int c = 0; c < 3; c++) dots0[c] = d0.w * b3[c];
        #pragma unroll
        for (int kq = 0; kq < 5; kq++) {
            float4 a0 = *(const float4*)(phi_s + (size_t)p * 20 + kq * 4);
            #pragma unroll
            for (int c = 0; c < 3; c++) {
                dots0[c] = fmaf(a0.x, wreg[c][kq*4+0], dots0[c]);
                dots0[c] = fmaf(a0.y, wreg[c][kq*4+1], dots0[c]);
                dots0[c] = fmaf(a0.z, wreg[c][kq*4+2], dots0[c]);
                dots0[c] = fmaf(a0.w, wreg[c][kq*4+3], dots0[c]);
            }
        }
        size_t xb = (size_t)j0 * 384;
        float xq0 = x[xb + h*64 + lane];
        float xr0 = x[xb + (2+h)*64 + lane];
        float xm0 = x[xb + (4+h)*64 + lane];
        float m00 = mu_in[((size_t)j0*3 + 0)*128 + f];
        float m01 = mu_in[((size_t)j0*3 + 1)*128 + f];
        float m02 = mu_in[((size_t)j0*3 + 2)*128 + f];
        float xxq0 = dots0[0] * xq0, xxr0 = dots0[1] * xr0, xxm0 = dots0[2] * xm0;
        accq += xxq0;
        acc0 += xxr0*d0.x + xxm0*m00;
        acc1 += xxr0*d0.y + xxm0*m01;
        acc2 += xxr0*d0.z + xxm0*m02;
    }
    q[(size_t)ia*128 + f] += accq;
    mu_out[((size_t)ia*3 + 0)*128 + f] = mu_in[((size_t)ia*3 + 0)*128 + f] + acc0;
    mu_out[((size_t)ia*3 + 1)*128 + f] = mu_in[((size_t)ia*3 + 1)*128 + f] + acc1;
    mu_out[((size_t)ia*3 + 2)*128 + f] = mu_in[((size_t)ia*3 + 2)*128 + f] + acc2;
}

extern "C" void kernel_launch(void* const* d_in, const int* in_sizes, int n_in,
                              void* d_out, int out_size, void* d_ws, size_t ws_size,
                              hipStream_t stream)
{
    const int*   Z       = (const int*)d_in[0];
    const float* r_ij    = (const float*)d_in[1];
    const int*   idx_i   = (const int*)d_in[2];
    const int*   idx_j   = (const int*)d_in[3];
    const int*   idx_m   = (const int*)d_in[4];
    const float* e_field = (const float*)d_in[5];
    const float* emb     = (const float*)d_in[6];
    const float* filt_W  = (const float*)d_in[7];
    const float* filt_b  = (const float*)d_in[8];
    const float* iW1     = (const float*)d_in[9];
    const float* ib1     = (const float*)d_in[10];
    const float* iW2     = (const float*)d_in[11];
    const float* ib2     = (const float*)d_in[12];
    const float* sW1     = (const float*)d_in[13];
    const float* sb1     = (const float*)d_in[14];
    const float* sW2     = (const float*)d_in[15];
    const float* sb2     = (const float*)d_in[16];
    const float* vW      = (const float*)d_in[17];
    const float* mmW     = (const float*)d_in[18];
    const float* mW1     = (const float*)d_in[19];
    const float* mb1     = (const float*)d_in[20];
    const float* mW2     = (const float*)d_in[21];
    const float* mb2     = (const float*)d_in[22];
    float* out = (float*)d_out;

    float* base = (float*)d_ws;
    size_t off = 0;
    auto alloc = [&](size_t n) { float* p = base + off; off += (n + 255) & ~(size_t)255; return p; };
    float* q     = alloc((size_t)NA*128);
    float* mu_a  = alloc((size_t)NA*384);
    float* mu_b  = alloc((size_t)NA*384);
    float* s384  = alloc((size_t)NA*384);   // x, then a_v (non-overlapping lifetimes)
    float* mumix = alloc((size_t)NA*768);
    float* Eat   = alloc((size_t)NA*3);
    float* phi_s = alloc((size_t)NE*20);
    float4* df_s = (float4*)alloc((size_t)NE*4);
    int* rowptr  = (int*)alloc(NA + 1);
    int* counts  = (int*)alloc(NA);
    int* cursor  = (int*)alloc(NA);
    int* j_s     = (int*)alloc(NE);
    unsigned short* wth = (unsigned short*)alloc(344064 + 256);
    unsigned short* wtl = (unsigned short*)alloc(344064 + 256);
    (void)ws_size; (void)in_sizes; (void)n_in; (void)out_size;

    // --- weight prep descriptors (per t: iW1,iW2,sW1,sW2,vW,mmW,mW1,mW2) -------
    WPack P;
    size_t woff = 0;
    unsigned short* WH[3][8];
    unsigned short* WL[3][8];
    int nw = 0;
    auto reg = [&](const float* src, int K, int N, int t, int slot) {
        P.w[nw].src = src; P.w[nw].dh = wth + woff; P.w[nw].dl = wtl + woff;
        P.w[nw].K = K; P.w[nw].N = N;
        WH[t][slot] = wth + woff; WL[t][slot] = wtl + woff;
        woff += (size_t)K * N; nw++;
    };
    for (int t = 0; t < 3; t++) {
        reg(iW1 + t*128*128, 128, 128, t, 0);
        reg(iW2 + t*128*384, 128, 384, t, 1);
        reg(sW1 + t*128*128, 128, 128, t, 2);
        reg(sW2 + t*128*128, 128, 128, t, 3);
        reg(vW  + t*128*128, 128, 128, t, 4);
        reg(mmW + t*128*256, 128, 256, t, 5);
        reg(mW1 + t*256*128, 256, 128, t, 6);
        reg(mW2 + t*128*384, 128, 384, t, 7);
    }

    k_wprep       <<<dim3(24, 24),          256, 0, stream>>>(P);
    k_init        <<<(NA*384 + 255)/256,    256, 0, stream>>>(Z, idx_m, emb, e_field, q, mu_a, Eat, counts, cursor);
    k_count       <<<(NE + 255)/256,        256, 0, stream>>>(idx_i, counts);
    k_scan        <<<1,                     256, 0, stream>>>(counts, rowptr);
    k_geom_scatter<<<(NE + 255)/256,        256, 0, stream>>>(r_ij, idx_i, idx_j, rowptr, cursor,
                                                              phi_s, df_s, j_s);

    const int G32   = (NA + 31) / 32;       // 313
    const int G64x3 = (NA*3 + 63) / 64;     // 469
    float* mu_cur = mu_a;
    float* mu_nxt = mu_b;
    for (int t = 0; t < 3; t++) {
        // Interaction MLP: x = silu(q@iW1+b1)@iW2+b2
        k_mlp<128,384,0,0><<<G32, 256, 0, stream>>>(
            q, nullptr, WH[t][0], WL[t][0], ib1 + t*128, WH[t][1], WL[t][1], ib2 + t*384,
            s384, nullptr, nullptr, nullptr, nullptr, nullptr, 0, NA);
        // edge message passing (owner-exclusive, no atomics)
        k_edge6<<<NA/2, 256, 0, stream>>>(t, phi_s, df_s, j_s, rowptr, s384,
                                          mu_cur, filt_W, filt_b, q, mu_nxt);
        { float* tmp = mu_cur; mu_cur = mu_nxt; mu_nxt = tmp; }
        // FieldInteraction: a_v = mu@vW; then sMLP with fused field update
        k_gmm2<0><<<dim3(G64x3, 2), 256, 0, stream>>>(mu_cur, WH[t][4], WL[t][4], nullptr, s384, NA*3, 128, 128);
        k_mlp<128,128,0,1><<<G32, 256, 0, stream>>>(
            q, nullptr, WH[t][2], WL[t][2], sb1 + t*128, WH[t][3], WL[t][3], sb2 + t*128,
            nullptr, s384, Eat, nullptr, mu_cur, nullptr, 0, NA);
        // Mixing: mumix = mu@mmW; mMLP with ctx prologue + fused mixupd (+pack)
        k_gmm2<0><<<dim3(G64x3, 4), 256, 0, stream>>>(mu_cur, WH[t][5], WL[t][5], nullptr, mumix, NA*3, 128, 256);
        k_mlp<256,384,1,2><<<G32, 256, 0, stream>>>(
            q, mumix, WH[t][6], WL[t][6], mb1 + t*128, WH[t][7], WL[t][7], mb2 + t*384,
            nullptr, nullptr, nullptr, q, mu_cur, out, (t == 2) ? 1 : 0, NA);
    }
}

// Round 8
// 1019.655 us; speedup vs baseline: 2.9680x; 2.9680x over previous
//
#include <hip/hip_runtime.h>

#define NA 10000
#define NE 320000

typedef short short8 __attribute__((ext_vector_type(8)));
typedef unsigned short us4 __attribute__((ext_vector_type(4)));
typedef float f32x4 __attribute__((ext_vector_type(4)));

__device__ __forceinline__ float silu_f(float v) { return v / (1.0f + __expf(-v)); }

__device__ __forceinline__ void split_bf16(float x, unsigned short& h, unsigned short& l)
{
    unsigned int u = __float_as_uint(x);
    h = (unsigned short)(u >> 16);
    float hf = __uint_as_float((unsigned int)h << 16);
    unsigned int ul = __float_as_uint(x - hf) + 0x8000u;
    l = (unsigned short)(ul >> 16);
}

// ---------------- init ----------------------------------------------------------
__global__ __launch_bounds__(256) void k_init(
    const int* __restrict__ Z, const int* __restrict__ idx_m,
    const float* __restrict__ emb, const float* __restrict__ e_field,
    float* __restrict__ q, float* __restrict__ mu,
    float* __restrict__ Eat, int* __restrict__ counts, int* __restrict__ cursor)
{
    int gid = blockIdx.x * 256 + threadIdx.x;
    if (gid < NA * 384) mu[gid] = 0.0f;
    if (gid < NA * 128) {
        int i = gid >> 7, f = gid & 127;
        q[gid] = emb[Z[i] * 128 + f];
    }
    if (gid < NA * 3) {
        int i = gid / 3, d = gid - i * 3;
        Eat[gid] = e_field[idx_m[i] * 3 + d];
    }
    if (gid < NA) { counts[gid] = 0; cursor[gid] = 0; }
}

// ---------------- histogram idx_i -----------------------------------------------
__global__ __launch_bounds__(256) void k_count(
    const int* __restrict__ idx_i, int* __restrict__ counts)
{
    int e = blockIdx.x * 256 + threadIdx.x;
    if (e < NE) atomicAdd(&counts[idx_i[e]], 1);
}

// ---------------- exclusive scan -------------------------------------------------
__global__ __launch_bounds__(256) void k_scan(const int* __restrict__ counts,
                                              int* __restrict__ rowptr)
{
    __shared__ int part[256];
    int tid = threadIdx.x;
    const int CH = (NA + 255) / 256;
    int base = tid * CH;
    int s = 0;
    for (int i2 = 0; i2 < CH; i2++) {
        int idx = base + i2;
        if (idx < NA) s += counts[idx];
    }
    part[tid] = s;
    __syncthreads();
    for (int ofs = 1; ofs < 256; ofs <<= 1) {
        int v = part[tid];
        int add = (tid >= ofs) ? part[tid - ofs] : 0;
        __syncthreads();
        part[tid] = v + add;
        __syncthreads();
    }
    int run = (tid > 0) ? part[tid - 1] : 0;
    for (int i2 = 0; i2 < CH; i2++) {
        int idx = base + i2;
        if (idx < NA) { rowptr[idx] = run; run += counts[idx]; }
        else if (idx == NA) rowptr[NA] = run;
    }
}

// ---------------- geometry + scatter into CSR order -----------------------------
__global__ __launch_bounds__(256) void k_geom_scatter(
    const float* __restrict__ r_ij, const int* __restrict__ idx_i,
    const int* __restrict__ idx_j, const int* __restrict__ rowptr,
    int* __restrict__ cursor, float* __restrict__ phi_s,
    float4* __restrict__ df_s, int* __restrict__ j_s)
{
    int e = blockIdx.x * 256 + threadIdx.x;
    if (e >= NE) return;
    float x = r_ij[e*3+0], y = r_ij[e*3+1], z = r_ij[e*3+2];
    float d = sqrtf(x*x + y*y + z*z);
    float inv = 1.0f / d;
    float fc = (d < 5.0f) ? 0.5f * (__cosf(d * 0.628318530717958648f) + 1.0f) : 0.0f;
    int i = idx_i[e];
    int pos = rowptr[i] + atomicAdd(&cursor[i], 1);
    float4 dv; dv.x = x*inv; dv.y = y*inv; dv.z = z*inv; dv.w = fc;
    df_s[pos] = dv;
    j_s[pos] = idx_j[e];
    const float invw = 19.0f / 5.0f;
    float ph[20];
    #pragma unroll
    for (int k = 0; k < 20; k++) {
        float off = (5.0f / 19.0f) * (float)k;
        float u = (d - off) * invw;
        ph[k] = __expf(-0.5f * u * u) * fc;
    }
    #pragma unroll
    for (int c = 0; c < 5; c++) {
        float4 pv; pv.x = ph[c*4]; pv.y = ph[c*4+1]; pv.z = ph[c*4+2]; pv.w = ph[c*4+3];
        *(float4*)(phi_s + (size_t)pos*20 + c*4) = pv;
    }
}

// ---------------- weight prep: hi/lo bf16 split, MFMA-fragment-linear -----------
struct WDesc { const float* src; unsigned short* dh; unsigned short* dl; int K; int N; };
struct WPack { WDesc w[24]; };

__global__ __launch_bounds__(256) void k_wprep(WPack P)
{
    WDesc d = P.w[blockIdx.y];
    int kBlks = d.K >> 5, nStrips = d.N >> 4;
    int total = nStrips * kBlks * 64;
    int g = blockIdx.x * 256 + threadIdx.x;
    if (g >= total) return;
    int lane = g & 63, rem = g >> 6;
    int kb = rem % kBlks, sIdx = rem / kBlks;
    int m16 = lane & 15, quad = lane >> 4;
    int n = sIdx * 16 + m16;
    int kbase = kb * 32 + quad * 8;
    size_t dofs = (size_t)g * 8;
    #pragma unroll
    for (int jj = 0; jj < 8; jj++) {
        unsigned short h, l;
        split_bf16(d.src[(size_t)(kbase + jj) * d.N + n], h, l);
        d.dh[dofs + jj] = h;
        d.dl[dofs + jj] = l;
    }
}

// ---------------- MFMA GEMM (bf16 split-3), 64x64 tile --------------------------
template<int ACT>
__global__ __launch_bounds__(256) void k_gmm2(
    const float* __restrict__ A,
    const unsigned short* __restrict__ Bh, const unsigned short* __restrict__ Bl,
    const float* __restrict__ bias, float* __restrict__ C,
    int M, int K, int N)
{
    __shared__ unsigned short Ahs[64 * 40];
    __shared__ unsigned short Als[64 * 40];
    int tid = threadIdx.x, lane = tid & 63, wv = tid >> 6;
    int i0 = blockIdx.x * 64, n0 = blockIdx.y * 64;
    int m16 = lane & 15, quad = lane >> 4;
    int kBlks = K >> 5;
    int sIdx = blockIdx.y * 4 + wv;

    f32x4 acc[4];
    #pragma unroll
    for (int a = 0; a < 4; a++) acc[a] = 0.0f;

    for (int kb = 0; kb < kBlks; kb++) {
        int k0 = kb << 5;
        __syncthreads();
        #pragma unroll
        for (int s = 0; s < 2; s++) {
            int idx = s * 256 + tid;
            int r = idx >> 3, c4 = (idx & 7) << 2;
            float4 v = {0.f, 0.f, 0.f, 0.f};
            if (i0 + r < M) v = *(const float4*)(A + (size_t)(i0 + r) * K + k0 + c4);
            unsigned short h0,l0,h1,l1,h2,l2,h3,l3;
            split_bf16(v.x, h0, l0); split_bf16(v.y, h1, l1);
            split_bf16(v.z, h2, l2); split_bf16(v.w, h3, l3);
            us4 hv = {h0, h1, h2, h3}, lv = {l0, l1, l2, l3};
            *(us4*)(Ahs + r * 40 + c4) = hv;
            *(us4*)(Als + r * 40 + c4) = lv;
        }
        __syncthreads();
        size_t bofs = (((size_t)sIdx * kBlks + kb) * 64 + lane) * 8;
        short8 bh = *(const short8*)(Bh + bofs);
        short8 bl = *(const short8*)(Bl + bofs);
        #pragma unroll
        for (int tm = 0; tm < 4; tm++) {
            short8 ah = *(const short8*)(Ahs + (tm * 16 + m16) * 40 + quad * 8);
            short8 al = *(const short8*)(Als + (tm * 16 + m16) * 40 + quad * 8);
            acc[tm] = __builtin_amdgcn_mfma_f32_16x16x32_bf16(ah, bh, acc[tm], 0, 0, 0);
            acc[tm] = __builtin_amdgcn_mfma_f32_16x16x32_bf16(ah, bl, acc[tm], 0, 0, 0);
            acc[tm] = __builtin_amdgcn_mfma_f32_16x16x32_bf16(al, bh, acc[tm], 0, 0, 0);
        }
    }
    int col = n0 + wv * 16 + m16;
    float bv = bias ? bias[col] : 0.0f;
    #pragma unroll
    for (int tm = 0; tm < 4; tm++) {
        #pragma unroll
        for (int r = 0; r < 4; r++) {
            int row = i0 + tm * 16 + quad * 4 + r;
            if (row < M) {
                float v = acc[tm][r] + bv;
                if (ACT) v = silu_f(v);
                C[(size_t)row * N + col] = v;
            }
        }
    }
}

// ---------------- fused MLP with prologue/epilogue variants ----------------------
// PRO: 0 = A is [M,K1] dense; 1 = ctx mode (K1=256): cols 0..127 from q,
//      cols 128..255 = ||mu_V|| computed from mumix on the fly.
// EPI: 0 = write C = h2 + b2
//      1 = field: a_s consumed in-place -> mu += a_s*E - (a_v.E)a_v
//      2 = mixupd: y staged in LDS; q += yq + yqm*sdot; mu += ym*mu_W;
//          if last, also write packed out [N,4,128].
template<int K1, int N2, int PRO, int EPI>
__global__ __launch_bounds__(256, 2) void k_mlp(
    const float* __restrict__ A, const float* __restrict__ mumix,
    const unsigned short* __restrict__ B1h, const unsigned short* __restrict__ B1l,
    const float* __restrict__ b1,
    const unsigned short* __restrict__ B2h, const unsigned short* __restrict__ B2l,
    const float* __restrict__ b2,
    float* __restrict__ C,
    const float* __restrict__ av, const float* __restrict__ Eat,
    float* __restrict__ qRW, float* __restrict__ muRW,
    float* __restrict__ outPk, int last, int M)
{
    const int KB1 = K1 / 32;
    const int S2  = N2 / 64;
    __shared__ unsigned short A1h[32 * 40];
    __shared__ unsigned short A1l[32 * 40];
    __shared__ unsigned short Hh[32 * 136];
    __shared__ unsigned short Hl[32 * 136];
    __shared__ float Ys[EPI == 2 ? 32 * 384 : 1];

    int tid = threadIdx.x, lane = tid & 63, wv = tid >> 6;
    int i0 = blockIdx.x * 32;
    int m16 = lane & 15, quad = lane >> 4;

    // ---- stage 1: h = silu(A@W1 + b1) ----
    f32x4 acc1[2][2];
    #pragma unroll
    for (int s = 0; s < 2; s++)
        #pragma unroll
        for (int tm = 0; tm < 2; tm++) acc1[s][tm] = 0.0f;

    for (int kb = 0; kb < KB1; kb++) {
        int k0 = kb << 5;
        __syncthreads();
        {
            int r = tid >> 3, c4 = (tid & 7) << 2;
            int row = i0 + r;
            float4 v = {0.f, 0.f, 0.f, 0.f};
            if (row < M) {
                if (PRO == 0) {
                    v = *(const float4*)(A + (size_t)row * K1 + k0 + c4);
                } else {
                    int g = k0 + c4;
                    if (g < 128) {
                        v = *(const float4*)(A + (size_t)row * 128 + g);
                    } else {
                        int f = g - 128;
                        float4 v0 = *(const float4*)(mumix + ((size_t)row*3 + 0)*256 + f);
                        float4 v1 = *(const float4*)(mumix + ((size_t)row*3 + 1)*256 + f);
                        float4 v2 = *(const float4*)(mumix + ((size_t)row*3 + 2)*256 + f);
                        v.x = sqrtf(v0.x*v0.x + v1.x*v1.x + v2.x*v2.x + 1e-8f);
                        v.y = sqrtf(v0.y*v0.y + v1.y*v1.y + v2.y*v2.y + 1e-8f);
                        v.z = sqrtf(v0.z*v0.z + v1.z*v1.z + v2.z*v2.z + 1e-8f);
                        v.w = sqrtf(v0.w*v0.w + v1.w*v1.w + v2.w*v2.w + 1e-8f);
                    }
                }
            }
            unsigned short h0,l0,h1,l1,h2,l2,h3,l3;
            split_bf16(v.x, h0, l0); split_bf16(v.y, h1, l1);
            split_bf16(v.z, h2, l2); split_bf16(v.w, h3, l3);
            us4 hv = {h0, h1, h2, h3}, lv = {l0, l1, l2, l3};
            *(us4*)(A1h + r * 40 + c4) = hv;
            *(us4*)(A1l + r * 40 + c4) = lv;
        }
        __syncthreads();
        #pragma unroll
        for (int tm = 0; tm < 2; tm++) {
            short8 ah = *(const short8*)(A1h + (tm * 16 + m16) * 40 + quad * 8);
            short8 al = *(const short8*)(A1l + (tm * 16 + m16) * 40 + quad * 8);
            #pragma unroll
            for (int s = 0; s < 2; s++) {
                int sIdx = wv * 2 + s;
                size_t bofs = (((size_t)sIdx * KB1 + kb) * 64 + lane) * 8;
                short8 bh = *(const short8*)(B1h + bofs);
                short8 bl = *(const short8*)(B1l + bofs);
                acc1[s][tm] = __builtin_amdgcn_mfma_f32_16x16x32_bf16(ah, bh, acc1[s][tm], 0, 0, 0);
                acc1[s][tm] = __builtin_amdgcn_mfma_f32_16x16x32_bf16(ah, bl, acc1[s][tm], 0, 0, 0);
                acc1[s][tm] = __builtin_amdgcn_mfma_f32_16x16x32_bf16(al, bh, acc1[s][tm], 0, 0, 0);
            }
        }
    }
    __syncthreads();
    #pragma unroll
    for (int s = 0; s < 2; s++) {
        int col = wv * 32 + s * 16 + m16;
        float bb = b1[col];
        #pragma unroll
        for (int tm = 0; tm < 2; tm++) {
            #pragma unroll
            for (int r = 0; r < 4; r++) {
                int row = tm * 16 + quad * 4 + r;
                float v = silu_f(acc1[s][tm][r] + bb);
                unsigned short h, l;
                split_bf16(v, h, l);
                Hh[row * 136 + col] = h;
                Hl[row * 136 + col] = l;
            }
        }
    }
    __syncthreads();

    // ---- stage 2: h2 = h@W2 ----
    f32x4 acc2[S2][2];
    #pragma unroll
    for (int s = 0; s < S2; s++)
        #pragma unroll
        for (int tm = 0; tm < 2; tm++) acc2[s][tm] = 0.0f;

    #pragma unroll
    for (int kb = 0; kb < 4; kb++) {
        short8 ah[2], al[2];
        #pragma unroll
        for (int tm = 0; tm < 2; tm++) {
            ah[tm] = *(const short8*)(Hh + (tm * 16 + m16) * 136 + kb * 32 + quad * 8);
            al[tm] = *(const short8*)(Hl + (tm * 16 + m16) * 136 + kb * 32 + quad * 8);
        }
        #pragma unroll
        for (int s = 0; s < S2; s++) {
            int sIdx = wv * S2 + s;
            size_t bofs = (((size_t)sIdx * 4 + kb) * 64 + lane) * 8;
            short8 bh = *(const short8*)(B2h + bofs);
            short8 bl = *(const short8*)(B2l + bofs);
            #pragma unroll
            for (int tm = 0; tm < 2; tm++) {
                acc2[s][tm] = __builtin_amdgcn_mfma_f32_16x16x32_bf16(ah[tm], bh, acc2[s][tm], 0, 0, 0);
                acc2[s][tm] = __builtin_amdgcn_mfma_f32_16x16x32_bf16(ah[tm], bl, acc2[s][tm], 0, 0, 0);
                acc2[s][tm] = __builtin_amdgcn_mfma_f32_16x16x32_bf16(al[tm], bh, acc2[s][tm], 0, 0, 0);
            }
        }
    }

    if (EPI == 0) {
        #pragma unroll
        for (int s = 0; s < S2; s++) {
            int col = (wv * S2 + s) * 16 + m16;
            float bb = b2 ? b2[col] : 0.0f;
            #pragma unroll
            for (int tm = 0; tm < 2; tm++) {
                #pragma unroll
                for (int r = 0; r < 4; r++) {
                    int row = i0 + tm * 16 + quad * 4 + r;
                    if (row < M) C[(size_t)row * N2 + col] = acc2[s][tm][r] + bb;
                }
            }
        }
    } else if (EPI == 1) {
        #pragma unroll
        for (int s = 0; s < S2; s++) {
            int col = (wv * S2 + s) * 16 + m16;
            float bb = b2[col];
            #pragma unroll
            for (int tm = 0; tm < 2; tm++) {
                #pragma unroll
                for (int r = 0; r < 4; r++) {
                    int row = i0 + tm * 16 + quad * 4 + r;
                    if (row < M) {
                        float as = acc2[s][tm][r] + bb;
                        float E0 = Eat[row*3+0], E1 = Eat[row*3+1], E2 = Eat[row*3+2];
                        size_t b0 = ((size_t)row*3 + 0)*128 + col;
                        size_t b1o = ((size_t)row*3 + 1)*128 + col;
                        size_t b2o = ((size_t)row*3 + 2)*128 + col;
                        float a0 = av[b0], a1 = av[b1o], a2 = av[b2o];
                        float dot = a0*E0 + a1*E1 + a2*E2;
                        muRW[b0] += as*E0 - dot*a0;
                        muRW[b1o] += as*E1 - dot*a1;
                        muRW[b2o] += as*E2 - dot*a2;
                    }
                }
            }
        }
    } else {
        #pragma unroll
        for (int s = 0; s < S2; s++) {
            int col = (wv * S2 + s) * 16 + m16;
            float bb = b2[col];
            #pragma unroll
            for (int tm = 0; tm < 2; tm++) {
                #pragma unroll
                for (int r = 0; r < 4; r++) {
                    int row = tm * 16 + quad * 4 + r;
                    Ys[row * 384 + col] = acc2[s][tm][r] + bb;
                }
            }
        }
        __syncthreads();
        int f = tid & 127;
        #pragma unroll
        for (int it = 0; it < 16; it++) {
            int row = (tid >> 7) + it * 2;
            int i = i0 + row;
            if (i < M) {
                float yq  = Ys[row * 384 + f];
                float ym  = Ys[row * 384 + 128 + f];
                float yqm = Ys[row * 384 + 256 + f];
                float sdot = 0.0f;
                float W[3];
                #pragma unroll
                for (int d = 0; d < 3; d++) {
                    float Vd = mumix[((size_t)i*3 + d)*256 + f];
                    W[d]     = mumix[((size_t)i*3 + d)*256 + 128 + f];
                    sdot += Vd * W[d];
                }
                float qn = qRW[(size_t)i*128 + f] + yq + yqm * sdot;
                qRW[(size_t)i*128 + f] = qn;
                float mun[3];
                #pragma unroll
                for (int d = 0; d < 3; d++) {
                    size_t mo = ((size_t)i*3 + d)*128 + f;
                    mun[d] = muRW[mo] + ym * W[d];
                    muRW[mo] = mun[d];
                }
                if (last) {
                    outPk[(size_t)i*512 + f] = qn;
                    #pragma unroll
                    for (int d = 0; d < 3; d++)
                        outPk[(size_t)i*512 + 128 + d*128 + f] = mun[d];
                }
            }
        }
    }
}

// ---------------- edge aggregation: atom-centric, feature-split, 4-edge batch ---
// (exact R5 k_edge4 — proven 201 µs/t, no spills)
__global__ __launch_bounds__(256, 3) void k_edge4(
    int t, const float* __restrict__ phi_s, const float4* __restrict__ df_s,
    const int* __restrict__ j_s, const int* __restrict__ rowptr,
    const float* __restrict__ x, const float* __restrict__ mu_in,
    const float* __restrict__ filt_W, const float* __restrict__ filt_b,
    float* __restrict__ q, float* __restrict__ mu_out)
{
    int lane = threadIdx.x & 63;
    int wv   = threadIdx.x >> 6;
    int ia   = blockIdx.x * 2 + (wv >> 1);
    int h    = wv & 1;
    int f    = lane + h * 64;

    float wreg[3][20];
    float b3[3];
    #pragma unroll
    for (int c = 0; c < 3; c++) {
        int col = t * 384 + (2*c + h) * 64 + lane;
        b3[c] = filt_b[col];
        #pragma unroll
        for (int k = 0; k < 20; k++)
            wreg[c][k] = filt_W[k * 1152 + col];
    }

    float accq = 0.0f, acc0 = 0.0f, acc1 = 0.0f, acc2 = 0.0f;
    int p0 = rowptr[ia], p1 = rowptr[ia + 1];
    int p = p0;
    for (; p + 4 <= p1; p += 4) {
        int jj[4]; float4 df[4];
        #pragma unroll
        for (int e = 0; e < 4; e++) { jj[e] = j_s[p + e]; df[e] = df_s[p + e]; }
        float dots[4][3];
        #pragma unroll
        for (int e = 0; e < 4; e++)
            #pragma unroll
            for (int c = 0; c < 3; c++) dots[e][c] = df[e].w * b3[c];
        #pragma unroll
        for (int kq = 0; kq < 5; kq++) {
            float4 a[4];
            #pragma unroll
            for (int e = 0; e < 4; e++)
                a[e] = *(const float4*)(phi_s + (size_t)(p + e) * 20 + kq * 4);
            #pragma unroll
            for (int e = 0; e < 4; e++) {
                #pragma unroll
                for (int c = 0; c < 3; c++) {
                    dots[e][c] = fmaf(a[e].x, wreg[c][kq*4+0], dots[e][c]);
                    dots[e][c] = fmaf(a[e].y, wreg[c][kq*4+1], dots[e][c]);
                    dots[e][c] = fmaf(a[e].z, wreg[c][kq*4+2], dots[e][c]);
                    dots[e][c] = fmaf(a[e].w, wreg[c][kq*4+3], dots[e][c]);
                }
            }
        }
        float xv[4][3], mv[4][3];
        #pragma unroll
        for (int e = 0; e < 4; e++) {
            size_t xb = (size_t)jj[e] * 384;
            xv[e][0] = x[xb + h*64 + lane];
            xv[e][1] = x[xb + (2+h)*64 + lane];
            xv[e][2] = x[xb + (4+h)*64 + lane];
            #pragma unroll
            for (int d = 0; d < 3; d++)
                mv[e][d] = mu_in[((size_t)jj[e]*3 + d)*128 + f];
        }
        #pragma unroll
        for (int e = 0; e < 4; e++) {
            float xxq = dots[e][0] * xv[e][0];
            float xxr = dots[e][1] * xv[e][1];
            float xxm = dots[e][2] * xv[e][2];
            accq += xxq;
            acc0 += xxr * df[e].x + xxm * mv[e][0];
            acc1 += xxr * df[e].y + xxm * mv[e][1];
            acc2 += xxr * df[e].z + xxm * mv[e][2];
        }
    }
    for (; p < p1; p++) {
        int j0 = j_s[p];
        float4 d0 = df_s[p];
        float dots0[3];
        #pragma unroll
        for (int c = 0; c < 3; c++) dots0[c] = d0.w * b3[c];
        #pragma unroll
        for (int kq = 0; kq < 5; kq++) {
            float4 a0 = *(const float4*)(phi_s + (size_t)p * 20 + kq * 4);
            #pragma unroll
            for (int c = 0; c < 3; c++) {
                dots0[c] = fmaf(a0.x, wreg[c][kq*4+0], dots0[c]);
                dots0[c] = fmaf(a0.y, wreg[c][kq*4+1], dots0[c]);
                dots0[c] = fmaf(a0.z, wreg[c][kq*4+2], dots0[c]);
                dots0[c] = fmaf(a0.w, wreg[c][kq*4+3], dots0[c]);
            }
        }
        size_t xb = (size_t)j0 * 384;
        float xq0 = x[xb + h*64 + lane];
        float xr0 = x[xb + (2+h)*64 + lane];
        float xm0 = x[xb + (4+h)*64 + lane];
        float m00 = mu_in[((size_t)j0*3 + 0)*128 + f];
        float m01 = mu_in[((size_t)j0*3 + 1)*128 + f];
        float m02 = mu_in[((size_t)j0*3 + 2)*128 + f];
        float xxq0 = dots0[0] * xq0, xxr0 = dots0[1] * xr0, xxm0 = dots0[2] * xm0;
        accq += xxq0;
        acc0 += xxr0*d0.x + xxm0*m00;
        acc1 += xxr0*d0.y + xxm0*m01;
        acc2 += xxr0*d0.z + xxm0*m02;
    }
    q[(size_t)ia*128 + f] += accq;
    mu_out[((size_t)ia*3 + 0)*128 + f] = mu_in[((size_t)ia*3 + 0)*128 + f] + acc0;
    mu_out[((size_t)ia*3 + 1)*128 + f] = mu_in[((size_t)ia*3 + 1)*128 + f] + acc1;
    mu_out[((size_t)ia*3 + 2)*128 + f] = mu_in[((size_t)ia*3 + 2)*128 + f] + acc2;
}

extern "C" void kernel_launch(void* const* d_in, const int* in_sizes, int n_in,
                              void* d_out, int out_size, void* d_ws, size_t ws_size,
                              hipStream_t stream)
{
    const int*   Z       = (const int*)d_in[0];
    const float* r_ij    = (const float*)d_in[1];
    const int*   idx_i   = (const int*)d_in[2];
    const int*   idx_j   = (const int*)d_in[3];
    const int*   idx_m   = (const int*)d_in[4];
    const float* e_field = (const float*)d_in[5];
    const float* emb     = (const float*)d_in[6];
    const float* filt_W  = (const float*)d_in[7];
    const float* filt_b  = (const float*)d_in[8];
    const float* iW1     = (const float*)d_in[9];
    const float* ib1     = (const float*)d_in[10];
    const float* iW2     = (const float*)d_in[11];
    const float* ib2     = (const float*)d_in[12];
    const float* sW1     = (const float*)d_in[13];
    const float* sb1     = (const float*)d_in[14];
    const float* sW2     = (const float*)d_in[15];
    const float* sb2     = (const float*)d_in[16];
    const float* vW      = (const float*)d_in[17];
    const float* mmW     = (const float*)d_in[18];
    const float* mW1     = (const float*)d_in[19];
    const float* mb1     = (const float*)d_in[20];
    const float* mW2     = (const float*)d_in[21];
    const float* mb2     = (const float*)d_in[22];
    float* out = (float*)d_out;

    float* base = (float*)d_ws;
    size_t off = 0;
    auto alloc = [&](size_t n) { float* p = base + off; off += (n + 255) & ~(size_t)255; return p; };
    float* q     = alloc((size_t)NA*128);
    float* mu_a  = alloc((size_t)NA*384);
    float* mu_b  = alloc((size_t)NA*384);
    float* s384  = alloc((size_t)NA*384);   // x, then a_v
    float* mumix = alloc((size_t)NA*768);
    float* Eat   = alloc((size_t)NA*3);
    float* phi_s = alloc((size_t)NE*20);
    float4* df_s = (float4*)alloc((size_t)NE*4);
    int* rowptr  = (int*)alloc(NA + 1);
    int* counts  = (int*)alloc(NA);
    int* cursor  = (int*)alloc(NA);
    int* j_s     = (int*)alloc(NE);
    unsigned short* wth = (unsigned short*)alloc(344064 + 256);
    unsigned short* wtl = (unsigned short*)alloc(344064 + 256);
    (void)ws_size; (void)in_sizes; (void)n_in; (void)out_size;

    WPack P;
    size_t woff = 0;
    unsigned short* WH[3][8];
    unsigned short* WL[3][8];
    int nw = 0;
    auto reg = [&](const float* src, int K, int N, int t, int slot) {
        P.w[nw].src = src; P.w[nw].dh = wth + woff; P.w[nw].dl = wtl + woff;
        P.w[nw].K = K; P.w[nw].N = N;
        WH[t][slot] = wth + woff; WL[t][slot] = wtl + woff;
        woff += (size_t)K * N; nw++;
    };
    for (int t = 0; t < 3; t++) {
        reg(iW1 + t*128*128, 128, 128, t, 0);
        reg(iW2 + t*128*384, 128, 384, t, 1);
        reg(sW1 + t*128*128, 128, 128, t, 2);
        reg(sW2 + t*128*128, 128, 128, t, 3);
        reg(vW  + t*128*128, 128, 128, t, 4);
        reg(mmW + t*128*256, 128, 256, t, 5);
        reg(mW1 + t*256*128, 256, 128, t, 6);
        reg(mW2 + t*128*384, 128, 384, t, 7);
    }

    k_wprep       <<<dim3(24, 24),          256, 0, stream>>>(P);
    k_init        <<<(NA*384 + 255)/256,    256, 0, stream>>>(Z, idx_m, emb, e_field, q, mu_a, Eat, counts, cursor);
    k_count       <<<(NE + 255)/256,        256, 0, stream>>>(idx_i, counts);
    k_scan        <<<1,                     256, 0, stream>>>(counts, rowptr);
    k_geom_scatter<<<(NE + 255)/256,        256, 0, stream>>>(r_ij, idx_i, idx_j, rowptr, cursor,
                                                              phi_s, df_s, j_s);

    const int G32   = (NA + 31) / 32;       // 313
    const int G64x3 = (NA*3 + 63) / 64;     // 469
    float* mu_cur = mu_a;
    float* mu_nxt = mu_b;
    for (int t = 0; t < 3; t++) {
        // Interaction MLP: x = silu(q@iW1+b1)@iW2+b2
        k_mlp<128,384,0,0><<<G32, 256, 0, stream>>>(
            q, nullptr, WH[t][0], WL[t][0], ib1 + t*128, WH[t][1], WL[t][1], ib2 + t*384,
            s384, nullptr, nullptr, nullptr, nullptr, nullptr, 0, NA);
        // edge message passing (owner-exclusive, no atomics)
        k_edge4<<<NA/2, 256, 0, stream>>>(t, phi_s, df_s, j_s, rowptr, s384,
                                          mu_cur, filt_W, filt_b, q, mu_nxt);
        { float* tmp = mu_cur; mu_cur = mu_nxt; mu_nxt = tmp; }
        // FieldInteraction: a_v = mu@vW; then sMLP with fused field update
        k_gmm2<0><<<dim3(G64x3, 2), 256, 0, stream>>>(mu_cur, WH[t][4], WL[t][4], nullptr, s384, NA*3, 128, 128);
        k_mlp<128,128,0,1><<<G32, 256, 0, stream>>>(
            q, nullptr, WH[t][2], WL[t][2], sb1 + t*128, WH[t][3], WL[t][3], sb2 + t*128,
            nullptr, s384, Eat, nullptr, mu_cur, nullptr, 0, NA);
        // Mixing: mumix = mu@mmW; mMLP with ctx prologue + fused mixupd (+pack)
        k_gmm2<0><<<dim3(G64x3, 4), 256, 0, stream>>>(mu_cur, WH[t][5], WL[t][5], nullptr, mumix, NA*3, 128, 256);
        k_mlp<256,384,1,2><<<G32, 256, 0, stream>>>(
            q, mumix, WH[t][6], WL[t][6], mb1 + t*128, WH[t][7], WL[t][7], mb2 + t*384,
            nullptr, nullptr, nullptr, q, mu_cur, out, (t == 2) ? 1 : 0, NA);
    }
}